// Round 8
// baseline (140.077 us; speedup 1.0000x reference)
//
#include <hip/hip_runtime.h>

#define NB 256
#define NJ 24
#define NV 6890
#define WT_LD 7168   // transposed-W row stride (floats): covers max OOB tail read, 16B-aligned

// ---------------------------------------------------------------------------
// Kernel 0: transpose weights (V,J) -> (J, WT_LD) in d_ws, coalesced both sides.
// ---------------------------------------------------------------------------
__global__ __launch_bounds__(256) void transpose_w2(const float* __restrict__ w,
                                                    float* __restrict__ wT) {
    __shared__ float Wl[256 * 25];   // row stride 25: gcd(25,32)=1
    const int v0 = blockIdx.x * 256, tid = threadIdx.x;
    const int nvalid = min(256, NV - v0);

    const float4* wg = reinterpret_cast<const float4*>(w + (size_t)v0 * NJ);
    const int nf4 = nvalid * NJ / 4;
    for (int i = tid; i < nf4; i += 256) {
        const float4 q = wg[i];
        const int f = i * 4, v = f / NJ, j = f % NJ;   // j in {0,4,...,20}
        float* d = &Wl[v * 25 + j];
        d[0] = q.x; d[1] = q.y; d[2] = q.z; d[3] = q.w;
    }
    __syncthreads();

#pragma unroll
    for (int j = 0; j < NJ; ++j)
        for (int v = tid; v < nvalid; v += 256)
            wT[(size_t)j * WT_LD + v0 + v] = Wl[v * 25 + j];   // coalesced store
}

// ---------------------------------------------------------------------------
// Kernel 1: kinematic chain via parallel ancestor doubling (unchanged, passing).
// ---------------------------------------------------------------------------
__device__ __constant__ int ANC[4][NJ] = {
  {-1, 0, 0, 0, 1, 2, 3, 4, 5, 6, 7, 8, 9, 9, 9,12,13,14,16,17,18,19,20,21},
  {-1,-1,-1,-1, 0, 0, 0, 1, 2, 3, 4, 5, 6, 6, 6, 9, 9, 9,13,14,16,17,18,19},
  {-1,-1,-1,-1,-1,-1,-1,-1,-1,-1, 0, 0, 0, 0, 0, 3, 3, 3, 6, 6, 9, 9,13,14},
  {-1,-1,-1,-1,-1,-1,-1,-1,-1,-1,-1,-1,-1,-1,-1,-1,-1,-1,-1,-1,-1,-1, 0, 0}};

__global__ __launch_bounds__(288) void chain2(
    const float* __restrict__ rot,      // (B,J,3,3)
    const float* __restrict__ joints,   // (B,J,3)
    float* __restrict__ posed_joints,   // (B,J,3)
    float* __restrict__ rel_tf)         // (B,J,4,4)
{
    __shared__ float Jl[NJ * 3];
    __shared__ float MA[NJ * 12];
    __shared__ float MB[NJ * 12];
    const int b = blockIdx.x, tid = threadIdx.x;
    const int j = tid / 12, e = tid % 12, r = e >> 2, c = e & 3;
    constexpr int par[NJ] = {0,0,0,0,1,2,3,4,5,6,7,8,9,9,9,12,13,14,16,17,18,19,20,21};

    if (tid < NJ * 3) Jl[tid] = joints[(size_t)b * NJ * 3 + tid];
    __syncthreads();

    float tv;
    if (c < 3) {
        tv = rot[(size_t)b * NJ * 9 + j * 9 + r * 3 + c];
    } else {
        tv = Jl[j * 3 + r];
        if (j > 0) tv -= Jl[par[j] * 3 + r];
    }
    MA[j * 12 + e] = tv;
    __syncthreads();

#define DSTEP(SRC, DST, K)                                                 \
    do {                                                                   \
        const int a = ANC[K][j];                                           \
        float nv;                                                          \
        if (a < 0) {                                                       \
            nv = SRC[j * 12 + e];                                          \
        } else {                                                           \
            nv = SRC[a * 12 + r * 4 + 0] * SRC[j * 12 + 0 + c]            \
               + SRC[a * 12 + r * 4 + 1] * SRC[j * 12 + 4 + c]            \
               + SRC[a * 12 + r * 4 + 2] * SRC[j * 12 + 8 + c];           \
            if (c == 3) nv += SRC[a * 12 + r * 4 + 3];                    \
        }                                                                  \
        DST[j * 12 + e] = nv;                                              \
        __syncthreads();                                                   \
    } while (0)

    DSTEP(MA, MB, 0);
    DSTEP(MB, MA, 1);
    DSTEP(MA, MB, 2);
    DSTEP(MB, MA, 3);

    const float aje = MA[j * 12 + e];
    if (c == 3) {
        posed_joints[(size_t)b * NJ * 3 + j * 3 + r] = aje;
        const float tj = MA[j * 12 + r * 4 + 0] * Jl[j * 3 + 0]
                       + MA[j * 12 + r * 4 + 1] * Jl[j * 3 + 1]
                       + MA[j * 12 + r * 4 + 2] * Jl[j * 3 + 2];
        rel_tf[(size_t)b * NJ * 16 + j * 16 + e] = aje - tj;
    } else {
        rel_tf[(size_t)b * NJ * 16 + j * 16 + e] = aje;
    }
    if (tid < NJ * 4) {
        const int j2 = tid >> 2, c2 = tid & 3;
        rel_tf[(size_t)b * NJ * 16 + j2 * 16 + 12 + c2] = (c2 == 3) ? 1.0f : 0.0f;
    }
}

// ---------------------------------------------------------------------------
// Kernel 2: vertex blend v4. 4 verts/thread (1024/block). Weights from
// transposed (J-major) layout -> coalesced float4; M via LDS b128 broadcasts
// amortized over 4 verts; verts/outputs via conflict-free padded LDS staging.
// ---------------------------------------------------------------------------
#define LVPB 1024
#define LTH 256

__global__ __launch_bounds__(LTH) void lbs4(
    const float* __restrict__ verts,    // (B,V,3)
    const float* __restrict__ wT,       // (J, WT_LD)
    const float* __restrict__ rel_tf,   // (B,J,4,4)
    float* __restrict__ out_verts)      // (B,V,3)
{
    __shared__ float Ml[NJ * 16];       // 1.5 KB
    __shared__ float Vio[LTH * 13];     // 13.3 KB; 12 floats + 1 pad per thread
    const int b = blockIdx.y, tid = threadIdx.x;
    const int v0 = blockIdx.x * LVPB;
    const int nvalid = min(LVPB, NV - v0);   // 1024 or 746

    for (int i = tid; i < NJ * 16; i += LTH)
        Ml[i] = rel_tf[(size_t)b * NJ * 16 + i];

    // stage verts: nvalid*3 floats via coalesced float2, scatter to padded slots
    {
        const float2* vg = reinterpret_cast<const float2*>(verts + ((size_t)b * NV + v0) * 3);
        const int nf2 = nvalid * 3 / 2;   // even: 1536 or 1119
        for (int i = tid; i < nf2; i += LTH) {
            const float2 q = vg[i];
            const int f0 = 2 * i, f1 = 2 * i + 1;
            Vio[(f0 / 12) * 13 + (f0 % 12)] = q.x;
            Vio[(f1 / 12) * 13 + (f1 % 12)] = q.y;
        }
    }
    __syncthreads();

    float px[4], py[4], pz[4];
#pragma unroll
    for (int k = 0; k < 4; ++k) {       // stride-13 reads: conflict-free
        px[k] = Vio[tid * 13 + k * 3 + 0];
        py[k] = Vio[tid * 13 + k * 3 + 1];
        pz[k] = Vio[tid * 13 + k * 3 + 2];
    }

    float acc[4][12];
#pragma unroll
    for (int k = 0; k < 4; ++k)
#pragma unroll
        for (int q = 0; q < 12; ++q) acc[k][q] = 0.0f;

    const int vbase = v0 + tid * 4;     // tail threads read into WT_LD pad (discarded)
#pragma unroll
    for (int jc = 0; jc < 3; ++jc) {    // 3 chunks x 8 joints: caps VGPR pressure
        float4 wv[8];
#pragma unroll
        for (int l = 0; l < 8; ++l) {
            const int j = jc * 8 + l;
            wv[l] = *reinterpret_cast<const float4*>(wT + (size_t)j * WT_LD + vbase);
        }
#pragma unroll
        for (int l = 0; l < 8; ++l) {
            const int j = jc * 8 + l;
            const float4 m0 = *reinterpret_cast<const float4*>(Ml + j * 16 + 0);
            const float4 m1 = *reinterpret_cast<const float4*>(Ml + j * 16 + 4);
            const float4 m2 = *reinterpret_cast<const float4*>(Ml + j * 16 + 8);
            const float m[12] = {m0.x, m0.y, m0.z, m0.w, m1.x, m1.y,
                                 m1.z, m1.w, m2.x, m2.y, m2.z, m2.w};
            const float wk[4] = {wv[l].x, wv[l].y, wv[l].z, wv[l].w};
#pragma unroll
            for (int k = 0; k < 4; ++k)
#pragma unroll
                for (int q = 0; q < 12; ++q) acc[k][q] += wk[k] * m[q];
        }
    }

    float o[4][3];
#pragma unroll
    for (int k = 0; k < 4; ++k)
#pragma unroll
        for (int r = 0; r < 3; ++r)
            o[k][r] = acc[k][r * 4 + 0] * px[k] + acc[k][r * 4 + 1] * py[k] +
                      acc[k][r * 4 + 2] * pz[k] + acc[k][r * 4 + 3];

    __syncthreads();   // done with Vio's input role
#pragma unroll
    for (int k = 0; k < 4; ++k)
        if (tid * 4 + k < nvalid) {
#pragma unroll
            for (int r = 0; r < 3; ++r) Vio[tid * 13 + k * 3 + r] = o[k][r];
        }
    __syncthreads();

    // coalesced float2 store
    {
        float2* og = reinterpret_cast<float2*>(out_verts + ((size_t)b * NV + v0) * 3);
        const int nf2 = nvalid * 3 / 2;
        for (int i = tid; i < nf2; i += LTH) {
            const int f0 = 2 * i, f1 = 2 * i + 1;
            og[i] = make_float2(Vio[(f0 / 12) * 13 + (f0 % 12)],
                                Vio[(f1 / 12) * 13 + (f1 % 12)]);
        }
    }
}

extern "C" void kernel_launch(void* const* d_in, const int* in_sizes, int n_in,
                              void* d_out, int out_size, void* d_ws, size_t ws_size,
                              hipStream_t stream) {
    const float* rot     = (const float*)d_in[0];   // (B,J,3,3)
    const float* joints  = (const float*)d_in[1];   // (B,J,3)
    const float* verts   = (const float*)d_in[2];   // (B,V,3)
    const float* weights = (const float*)d_in[3];   // (V,J)

    float* out = (float*)d_out;
    float* posed_verts  = out;                                   // B*V*3
    float* posed_joints = out + (size_t)NB * NV * 3;             // B*J*3
    float* rel_tf       = posed_joints + (size_t)NB * NJ * 3;    // B*J*16
    float* wT           = (float*)d_ws;                          // 24*7168 floats = 688 KB

    transpose_w2<<<(NV + 255) / 256, 256, 0, stream>>>(weights, wT);
    chain2<<<NB, 288, 0, stream>>>(rot, joints, posed_joints, rel_tf);

    const int nbx = (NV + LVPB - 1) / LVPB;   // 7
    lbs4<<<dim3(nbx, NB), LTH, 0, stream>>>(verts, wT, rel_tf, posed_verts);
}